// Round 1
// baseline (1738.004 us; speedup 1.0000x reference)
//
#include <hip/hip_runtime.h>

typedef unsigned short u16;
typedef unsigned int   u32;

typedef __attribute__((ext_vector_type(8))) __bf16 bf16x8;
typedef __attribute__((ext_vector_type(4))) float  f32x4;

__device__ __forceinline__ u16 f2bf(float f) {
  union { float f; u32 u; } v; v.f = f;
  return (u16)((v.u + 0x7fffu + ((v.u >> 16) & 1u)) >> 16);
}

// ---------- W1 [K=1024][N=1024] f32 -> W1t [N][K] bf16 ----------
__global__ __launch_bounds__(256) void transpose_w1_kernel(
    const float* __restrict__ W1, u16* __restrict__ W1t) {
  __shared__ float tile[64][65];
  const int k0 = blockIdx.x * 64, n0 = blockIdx.y * 64;
  const int tx = threadIdx.x & 63, ty = threadIdx.x >> 6;
#pragma unroll
  for (int i = 0; i < 16; ++i) {
    int r = ty + i * 4;
    tile[r][tx] = W1[(k0 + r) * 1024 + n0 + tx];
  }
  __syncthreads();
#pragma unroll
  for (int i = 0; i < 16; ++i) {
    int r = ty * 16 + i;
    W1t[(n0 + r) * 1024 + k0 + tx] = f2bf(tile[tx][r]);
  }
}

// ---------- pd[b][d] = dec[b]·W2[:,d] + W2_b[d] + W1_b[d] ----------
__global__ __launch_bounds__(256) void proj_dec_kernel(
    const float* __restrict__ dec, const float* __restrict__ W2,
    const float* __restrict__ W2b, const float* __restrict__ W1b,
    float* __restrict__ pd) {
  __shared__ float sdec[64 * 256];
  const int dl = threadIdx.x & 63;
  const int bg = threadIdx.x >> 6;
  const int d  = blockIdx.x * 64 + dl;
  float acc[16];
#pragma unroll
  for (int i = 0; i < 16; ++i) acc[i] = 0.f;
  for (int et = 0; et < 4; ++et) {
    __syncthreads();
#pragma unroll
    for (int i = 0; i < 64; ++i) {
      int flat = threadIdx.x + i * 256;
      sdec[flat] = dec[(flat >> 8) * 1024 + et * 256 + (flat & 255)];
    }
    __syncthreads();
    for (int e = 0; e < 256; ++e) {
      float w2 = W2[(et * 256 + e) * 1024 + d];
#pragma unroll
      for (int bb = 0; bb < 16; ++bb)
        acc[bb] += sdec[(bg * 16 + bb) * 256 + e] * w2;
    }
  }
  float bias = W2b[d] + W1b[d];
#pragma unroll
  for (int bb = 0; bb < 16; ++bb)
    pd[(bg * 16 + bb) * 1024 + d] = acc[bb] + bias;
}

// ---------- fused GEMM(bf16 MFMA) + tanh + V-dot -> scores [B,S] ----------
// grid: 2048 blocks (64 rows each), 512 threads = 8 waves in 2(m) x 4(n) grid.
// A-panel (64 x 1024 bf16) swizzled in LDS; B-frags straight from L2-resident W1t.
__global__ __launch_bounds__(512, 2) void score_kernel(
    const float* __restrict__ enc, const u16* __restrict__ W1t,
    const float* __restrict__ pd, const float* __restrict__ Vw,
    float* __restrict__ scores) {
  __shared__ __align__(16) u16 As[64 * 1024];  // 128 KB
  __shared__ float sc2[8][32];
  const int  tid  = threadIdx.x;
  const long row0 = (long)blockIdx.x * 64;
  const int  b    = (int)(row0 >> 11);  // 2048 rows per batch; 64 | 2048

  // stage A-panel fp32 -> bf16, XOR-swizzled (idx ^= (row&7)<<3 in u16 units)
  {
    const float* src = enc + row0 * 1024;
#pragma unroll
    for (int i = 0; i < 32; ++i) {
      int g   = tid + i * 512;      // float4 granule 0..16383
      int row = g >> 8;             // 256 granules per row
      int k   = (g & 255) * 4;
      float4 v = *reinterpret_cast<const float4*>(src + row * 1024 + k);
      u32 p0 = (u32)f2bf(v.x) | ((u32)f2bf(v.y) << 16);
      u32 p1 = (u32)f2bf(v.z) | ((u32)f2bf(v.w) << 16);
      int idx = row * 1024 + (k ^ ((row & 7) << 3));
      *reinterpret_cast<u32*>(&As[idx])     = p0;
      *reinterpret_cast<u32*>(&As[idx + 2]) = p1;
    }
  }
  __syncthreads();

  const int lane = tid & 63;
  const int wid  = tid >> 6;
  const int wm = wid >> 2, wn = wid & 3;
  const int l15 = lane & 15, l4 = lane >> 4;

  float part[2][4];
#pragma unroll
  for (int t = 0; t < 2; ++t)
#pragma unroll
    for (int r = 0; r < 4; ++r) part[t][r] = 0.f;

  const int rA0 = wm * 32 + l15;
  const int rA1 = rA0 + 16;
  const int sw0 = (rA0 & 7) << 3;
  const int sw1 = (rA1 & 7) << 3;

  for (int nc = 0; nc < 8; ++nc) {
    const int colbase = nc * 128 + wn * 32;
    const u16* bp0 = W1t + (colbase + l15) * 1024 + l4 * 8;
    const u16* bp1 = bp0 + 16 * 1024;
    f32x4 acc00 = {0,0,0,0}, acc01 = {0,0,0,0};
    f32x4 acc10 = {0,0,0,0}, acc11 = {0,0,0,0};
#pragma unroll
    for (int kk = 0; kk < 32; ++kk) {
      const int kb = kk * 32 + l4 * 8;
      bf16x8 a0 = *reinterpret_cast<const bf16x8*>(&As[rA0 * 1024 + (kb ^ sw0)]);
      bf16x8 a1 = *reinterpret_cast<const bf16x8*>(&As[rA1 * 1024 + (kb ^ sw1)]);
      bf16x8 b0 = *reinterpret_cast<const bf16x8*>(bp0 + kk * 32);
      bf16x8 b1 = *reinterpret_cast<const bf16x8*>(bp1 + kk * 32);
      acc00 = __builtin_amdgcn_mfma_f32_16x16x32_bf16(a0, b0, acc00, 0, 0, 0);
      acc01 = __builtin_amdgcn_mfma_f32_16x16x32_bf16(a0, b1, acc01, 0, 0, 0);
      acc10 = __builtin_amdgcn_mfma_f32_16x16x32_bf16(a1, b0, acc10, 0, 0, 0);
      acc11 = __builtin_amdgcn_mfma_f32_16x16x32_bf16(a1, b1, acc11, 0, 0, 0);
    }
    // epilogue: v = acc + pd;  t = tanh(v);  part += t * Vw
#pragma unroll
    for (int t = 0; t < 2; ++t) {
      const f32x4 accu0 = (t == 0) ? acc00 : acc10;
      const f32x4 accu1 = (t == 0) ? acc01 : acc11;
#pragma unroll
      for (int r = 0; r < 4; ++r) {
        int c0 = colbase + l15;
        float v0 = accu0[r] + pd[b * 1024 + c0];
        float v1 = accu1[r] + pd[b * 1024 + c0 + 16];
        float e0 = __expf(2.f * v0);
        float e1 = __expf(2.f * v1);
        float t0 = 1.f - 2.f * __builtin_amdgcn_rcpf(e0 + 1.f);
        float t1 = 1.f - 2.f * __builtin_amdgcn_rcpf(e1 + 1.f);
        part[t][r] += t0 * Vw[c0] + t1 * Vw[c0 + 16];
      }
    }
  }
  // reduce the 16 col-lanes of each row-group (C layout: col=l&15, row=(l>>4)*4+r)
#pragma unroll
  for (int t = 0; t < 2; ++t)
#pragma unroll
    for (int r = 0; r < 4; ++r) {
      float s = part[t][r];
      s += __shfl_xor(s, 1);
      s += __shfl_xor(s, 2);
      s += __shfl_xor(s, 4);
      s += __shfl_xor(s, 8);
      if (l15 == 0) sc2[wid][t * 16 + l4 * 4 + r] = s;
    }
  __syncthreads();
  if (tid < 64) {
    int wmf = tid >> 5, lr = tid & 31;
    float s = sc2[wmf * 4 + 0][lr] + sc2[wmf * 4 + 1][lr] +
              sc2[wmf * 4 + 2][lr] + sc2[wmf * 4 + 3][lr];
    scores[row0 + tid] = s;  // V_b omitted: uniform shift cancels in softmax
  }
}

// ---------- softmax over S=2048 per batch ----------
__global__ __launch_bounds__(512) void softmax_kernel(
    const float* __restrict__ scores, float* __restrict__ wout) {
  __shared__ float redm[8], reds[8];
  const int b = blockIdx.x, tid = threadIdx.x;
  float4 v = *reinterpret_cast<const float4*>(scores + b * 2048 + tid * 4);
  float m = fmaxf(fmaxf(v.x, v.y), fmaxf(v.z, v.w));
  for (int off = 32; off; off >>= 1) m = fmaxf(m, __shfl_xor(m, off));
  if ((tid & 63) == 0) redm[tid >> 6] = m;
  __syncthreads();
  m = fmaxf(fmaxf(fmaxf(redm[0], redm[1]), fmaxf(redm[2], redm[3])),
            fmaxf(fmaxf(redm[4], redm[5]), fmaxf(redm[6], redm[7])));
  float e0 = __expf(v.x - m), e1 = __expf(v.y - m);
  float e2 = __expf(v.z - m), e3 = __expf(v.w - m);
  float s = e0 + e1 + e2 + e3;
  for (int off = 32; off; off >>= 1) s += __shfl_xor(s, off);
  if ((tid & 63) == 0) reds[tid >> 6] = s;
  __syncthreads();
  s = reds[0] + reds[1] + reds[2] + reds[3] + reds[4] + reds[5] + reds[6] + reds[7];
  float inv = 1.0f / s;
  float4 o; o.x = e0 * inv; o.y = e1 * inv; o.z = e2 * inv; o.w = e3 * inv;
  *reinterpret_cast<float4*>(wout + b * 2048 + tid * 4) = o;
}

// ---------- context[b][e] = sum_s w[b][s] * enc[b][s][e] ----------
__global__ __launch_bounds__(256) void context_kernel(
    const float* __restrict__ w, const float* __restrict__ enc,
    float* __restrict__ ctx) {
  const int b = blockIdx.x;
  const int e = blockIdx.y * 256 + threadIdx.x;
  const float* ep = enc + (size_t)b * 2048 * 1024 + e;
  const float* wp = w + b * 2048;
  float acc = 0.f;
#pragma unroll 8
  for (int s = 0; s < 2048; ++s)
    acc += wp[s] * ep[(size_t)s * 1024];
  ctx[b * 1024 + e] = acc;
}

extern "C" void kernel_launch(void* const* d_in, const int* in_sizes, int n_in,
                              void* d_out, int out_size, void* d_ws, size_t ws_size,
                              hipStream_t stream) {
  const float* enc = (const float*)d_in[0];
  const float* dec = (const float*)d_in[1];
  const float* W1w = (const float*)d_in[2];
  const float* W1b = (const float*)d_in[3];
  const float* W2w = (const float*)d_in[4];
  const float* W2b = (const float*)d_in[5];
  const float* Vw  = (const float*)d_in[6];
  // d_in[7] = V_b: uniform additive shift on scores -> cancels in softmax.

  char* ws = (char*)d_ws;
  u16*   W1t    = (u16*)ws;                                  // 2 MB
  float* pd     = (float*)(ws + (2u << 20));                 // 256 KB
  float* scores = (float*)(ws + (2u << 20) + (256u << 10));  // 512 KB
  float* wout = (float*)d_out;            // [64*2048] attention weights
  float* ctx  = (float*)d_out + 64 * 2048;  // [64*1024] context

  transpose_w1_kernel<<<dim3(16, 16), 256, 0, stream>>>(W1w, W1t);
  proj_dec_kernel<<<16, 256, 0, stream>>>(dec, W2w, W2b, W1b, pd);
  score_kernel<<<2048, 512, 0, stream>>>(enc, W1t, pd, Vw, scores);
  softmax_kernel<<<64, 512, 0, stream>>>(scores, wout);
  context_kernel<<<dim3(64, 4), 256, 0, stream>>>(wout, enc, ctx);
}

// Round 2
// 1260.619 us; speedup vs baseline: 1.3787x; 1.3787x over previous
//
#include <hip/hip_runtime.h>

typedef unsigned short u16;
typedef unsigned int   u32;

typedef __attribute__((ext_vector_type(8))) __bf16 bf16x8;
typedef __attribute__((ext_vector_type(4))) float  f32x4;

__device__ __forceinline__ u16 f2bf(float f) {
  union { float f; u32 u; } v; v.f = f;
  return (u16)((v.u + 0x7fffu + ((v.u >> 16) & 1u)) >> 16);
}

// ---------- W1 [K=1024][N=1024] f32 -> W1t [N][K] bf16 ----------
__global__ __launch_bounds__(256) void transpose_w1_kernel(
    const float* __restrict__ W1, u16* __restrict__ W1t) {
  __shared__ float tile[64][65];
  const int k0 = blockIdx.x * 64, n0 = blockIdx.y * 64;
  const int tx = threadIdx.x & 63, ty = threadIdx.x >> 6;
#pragma unroll
  for (int i = 0; i < 16; ++i) {
    int r = ty + i * 4;
    tile[r][tx] = W1[(k0 + r) * 1024 + n0 + tx];
  }
  __syncthreads();
#pragma unroll
  for (int i = 0; i < 16; ++i) {
    int r = ty * 16 + i;
    W1t[(n0 + r) * 1024 + k0 + tx] = f2bf(tile[tx][r]);
  }
}

// ---------- pd[b][d] = dec[b]·W2[:,d] + W2_b[d] + W1_b[d] ----------
__global__ __launch_bounds__(256) void proj_dec_kernel(
    const float* __restrict__ dec, const float* __restrict__ W2,
    const float* __restrict__ W2b, const float* __restrict__ W1b,
    float* __restrict__ pd) {
  __shared__ float sdec[64 * 256];
  const int dl = threadIdx.x & 63;
  const int bg = threadIdx.x >> 6;
  const int d  = blockIdx.x * 64 + dl;
  float acc[16];
#pragma unroll
  for (int i = 0; i < 16; ++i) acc[i] = 0.f;
  for (int et = 0; et < 4; ++et) {
    __syncthreads();
#pragma unroll
    for (int i = 0; i < 64; ++i) {
      int flat = threadIdx.x + i * 256;
      sdec[flat] = dec[(flat >> 8) * 1024 + et * 256 + (flat & 255)];
    }
    __syncthreads();
    for (int e = 0; e < 256; ++e) {
      float w2 = W2[(et * 256 + e) * 1024 + d];
#pragma unroll
      for (int bb = 0; bb < 16; ++bb)
        acc[bb] += sdec[(bg * 16 + bb) * 256 + e] * w2;
    }
  }
  float bias = W2b[d] + W1b[d];
#pragma unroll
  for (int bb = 0; bb < 16; ++bb)
    pd[(bg * 16 + bb) * 1024 + d] = acc[bb] + bias;
}

// ---------- fused GEMM(bf16 MFMA) + tanh + V-dot -> scores [B,S] ----------
// 2048 blocks x 1024 threads (16 waves = 2m x 8n). 1 block/CU (128KB LDS),
// 4 waves/SIMD. Per-wave 32x32 sub-tile: 4 MFMA per (2 A-LDS + 2 B-L2) loads,
// with depth-1 register prefetch of B.
__global__ __launch_bounds__(1024, 4) void score_kernel(
    const float* __restrict__ enc, const u16* __restrict__ W1t,
    const float* __restrict__ pd, const float* __restrict__ Vw,
    float* __restrict__ scores) {
  __shared__ __align__(16) u16 As[64 * 1024];  // 128 KB
  __shared__ float sc2[16][32];
  const int  tid  = threadIdx.x;
  const long row0 = (long)blockIdx.x * 64;
  const int  b    = (int)(row0 >> 11);  // 2048 rows per batch

  // stage A-panel fp32 -> bf16, XOR-swizzled at 16B granules
  {
    const float* src = enc + row0 * 1024;
#pragma unroll
    for (int i = 0; i < 16; ++i) {
      int g   = tid + i * 1024;     // float4 granule 0..16383
      int row = g >> 8;
      int k   = (g & 255) * 4;      // u16 index, multiple of 4
      float4 v = *reinterpret_cast<const float4*>(src + row * 1024 + k);
      u32 p0 = (u32)f2bf(v.x) | ((u32)f2bf(v.y) << 16);
      u32 p1 = (u32)f2bf(v.z) | ((u32)f2bf(v.w) << 16);
      int idx = row * 1024 + (k ^ ((row & 7) << 3));
      *reinterpret_cast<u32*>(&As[idx])     = p0;
      *reinterpret_cast<u32*>(&As[idx + 2]) = p1;
    }
  }
  __syncthreads();

  const int lane = tid & 63;
  const int wid  = tid >> 6;
  const int wm = wid >> 3, wn = wid & 7;  // 2 m-groups(32 rows) x 8 n-groups(32 cols)
  const int l15 = lane & 15, l4 = lane >> 4;

  float part[2][4];
#pragma unroll
  for (int t = 0; t < 2; ++t)
#pragma unroll
    for (int r = 0; r < 4; ++r) part[t][r] = 0.f;

  const int rA0 = wm * 32 + l15;
  const int rA1 = rA0 + 16;
  const int sw0 = (rA0 & 7) << 3;
  const int sw1 = (rA1 & 7) << 3;

  for (int nc = 0; nc < 4; ++nc) {
    const int colbase = nc * 256 + wn * 32;
    const u16* bp0 = W1t + (colbase + l15) * 1024 + l4 * 8;
    const u16* bp1 = bp0 + 16 * 1024;
    f32x4 acc00 = {0,0,0,0}, acc01 = {0,0,0,0};
    f32x4 acc10 = {0,0,0,0}, acc11 = {0,0,0,0};
    bf16x8 b0 = *reinterpret_cast<const bf16x8*>(bp0);
    bf16x8 b1 = *reinterpret_cast<const bf16x8*>(bp1);
#pragma unroll
    for (int kk = 0; kk < 32; ++kk) {
      bf16x8 cb0 = b0, cb1 = b1;
      if (kk != 31) {  // depth-1 prefetch of next B pair
        b0 = *reinterpret_cast<const bf16x8*>(bp0 + (kk + 1) * 32);
        b1 = *reinterpret_cast<const bf16x8*>(bp1 + (kk + 1) * 32);
      }
      const int kb = kk * 32 + l4 * 8;
      bf16x8 a0 = *reinterpret_cast<const bf16x8*>(&As[rA0 * 1024 + (kb ^ sw0)]);
      bf16x8 a1 = *reinterpret_cast<const bf16x8*>(&As[rA1 * 1024 + (kb ^ sw1)]);
      acc00 = __builtin_amdgcn_mfma_f32_16x16x32_bf16(a0, cb0, acc00, 0, 0, 0);
      acc01 = __builtin_amdgcn_mfma_f32_16x16x32_bf16(a0, cb1, acc01, 0, 0, 0);
      acc10 = __builtin_amdgcn_mfma_f32_16x16x32_bf16(a1, cb0, acc10, 0, 0, 0);
      acc11 = __builtin_amdgcn_mfma_f32_16x16x32_bf16(a1, cb1, acc11, 0, 0, 0);
    }
    // epilogue: v = acc + pd; t = tanh(v); part += t * Vw
    const int   c0  = colbase + l15;
    const float pd0 = pd[b * 1024 + c0];
    const float pd1 = pd[b * 1024 + c0 + 16];
    const float vw0 = Vw[c0];
    const float vw1 = Vw[c0 + 16];
#pragma unroll
    for (int t = 0; t < 2; ++t) {
      const f32x4 au0 = (t == 0) ? acc00 : acc10;
      const f32x4 au1 = (t == 0) ? acc01 : acc11;
#pragma unroll
      for (int r = 0; r < 4; ++r) {
        float v0 = au0[r] + pd0;
        float v1 = au1[r] + pd1;
        float e0 = __expf(2.f * v0);
        float e1 = __expf(2.f * v1);
        float t0 = 1.f - 2.f * __builtin_amdgcn_rcpf(e0 + 1.f);
        float t1 = 1.f - 2.f * __builtin_amdgcn_rcpf(e1 + 1.f);
        part[t][r] += t0 * vw0 + t1 * vw1;
      }
    }
  }
  // reduce over the 16 col-lanes (C layout: col=l&15, row=(l>>4)*4+r)
#pragma unroll
  for (int t = 0; t < 2; ++t)
#pragma unroll
    for (int r = 0; r < 4; ++r) {
      float s = part[t][r];
      s += __shfl_xor(s, 1);
      s += __shfl_xor(s, 2);
      s += __shfl_xor(s, 4);
      s += __shfl_xor(s, 8);
      if (l15 == 0) sc2[wid][t * 16 + l4 * 4 + r] = s;
    }
  __syncthreads();
  if (tid < 64) {
    const int wmr = tid >> 5, lr = tid & 31;
    float s = 0.f;
#pragma unroll
    for (int j = 0; j < 8; ++j) s += sc2[wmr * 8 + j][lr];
    scores[row0 + tid] = s;  // V_b omitted: uniform shift cancels in softmax
  }
}

// ---------- softmax over S=2048 per batch ----------
__global__ __launch_bounds__(512) void softmax_kernel(
    const float* __restrict__ scores, float* __restrict__ wout) {
  __shared__ float redm[8], reds[8];
  const int b = blockIdx.x, tid = threadIdx.x;
  float4 v = *reinterpret_cast<const float4*>(scores + b * 2048 + tid * 4);
  float m = fmaxf(fmaxf(v.x, v.y), fmaxf(v.z, v.w));
  for (int off = 32; off; off >>= 1) m = fmaxf(m, __shfl_xor(m, off));
  if ((tid & 63) == 0) redm[tid >> 6] = m;
  __syncthreads();
  m = fmaxf(fmaxf(fmaxf(redm[0], redm[1]), fmaxf(redm[2], redm[3])),
            fmaxf(fmaxf(redm[4], redm[5]), fmaxf(redm[6], redm[7])));
  float e0 = __expf(v.x - m), e1 = __expf(v.y - m);
  float e2 = __expf(v.z - m), e3 = __expf(v.w - m);
  float s = e0 + e1 + e2 + e3;
  for (int off = 32; off; off >>= 1) s += __shfl_xor(s, off);
  if ((tid & 63) == 0) reds[tid >> 6] = s;
  __syncthreads();
  s = reds[0] + reds[1] + reds[2] + reds[3] + reds[4] + reds[5] + reds[6] + reds[7];
  float inv = 1.0f / s;
  float4 o; o.x = e0 * inv; o.y = e1 * inv; o.z = e2 * inv; o.w = e3 * inv;
  *reinterpret_cast<float4*>(wout + b * 2048 + tid * 4) = o;
}

// ---------- context partials: cpart[b][ss][e] = sum_{s in ss} w*enc ----------
__global__ __launch_bounds__(256) void context_partial_kernel(
    const float* __restrict__ w, const float* __restrict__ enc,
    float* __restrict__ cpart) {
  const int b  = blockIdx.x;   // 64
  const int es = blockIdx.y;   // 4: e-range of 256
  const int ss = blockIdx.z;   // 8: s-range of 256
  const int e  = es * 256 + threadIdx.x;
  const float* ep = enc + ((size_t)b * 2048 + (size_t)ss * 256) * 1024 + e;
  const float* wp = w + b * 2048 + ss * 256;
  float acc = 0.f;
#pragma unroll 8
  for (int s = 0; s < 256; ++s)
    acc += wp[s] * ep[(size_t)s * 1024];
  cpart[((size_t)(b * 8 + ss)) * 1024 + e] = acc;
}

__global__ __launch_bounds__(256) void context_reduce_kernel(
    const float* __restrict__ cpart, float* __restrict__ ctx) {
  const int i = blockIdx.x * 256 + threadIdx.x;  // 64*1024
  const int b = i >> 10, e = i & 1023;
  float s = 0.f;
#pragma unroll
  for (int j = 0; j < 8; ++j) s += cpart[(size_t)(b * 8 + j) * 1024 + e];
  ctx[i] = s;
}

extern "C" void kernel_launch(void* const* d_in, const int* in_sizes, int n_in,
                              void* d_out, int out_size, void* d_ws, size_t ws_size,
                              hipStream_t stream) {
  const float* enc = (const float*)d_in[0];
  const float* dec = (const float*)d_in[1];
  const float* W1w = (const float*)d_in[2];
  const float* W1b = (const float*)d_in[3];
  const float* W2w = (const float*)d_in[4];
  const float* W2b = (const float*)d_in[5];
  const float* Vw  = (const float*)d_in[6];
  // d_in[7] = V_b: uniform additive shift on scores -> cancels in softmax.

  char* ws = (char*)d_ws;
  u16*   W1t    = (u16*)ws;                                  // 2 MB (dead after score)
  float* cpart  = (float*)ws;                                // 2 MB (reuses W1t region)
  float* pd     = (float*)(ws + (2u << 20));                 // 256 KB
  float* scores = (float*)(ws + (2u << 20) + (256u << 10));  // 512 KB
  float* wout = (float*)d_out;              // [64*2048] attention weights
  float* ctx  = (float*)d_out + 64 * 2048;  // [64*1024] context

  transpose_w1_kernel<<<dim3(16, 16), 256, 0, stream>>>(W1w, W1t);
  proj_dec_kernel<<<16, 256, 0, stream>>>(dec, W2w, W2b, W1b, pd);
  score_kernel<<<2048, 1024, 0, stream>>>(enc, W1t, pd, Vw, scores);
  softmax_kernel<<<64, 512, 0, stream>>>(scores, wout);
  context_partial_kernel<<<dim3(64, 4, 8), 256, 0, stream>>>(wout, enc, cpart);
  context_reduce_kernel<<<256, 256, 0, stream>>>(cpart, ctx);
}

// Round 3
// 760.013 us; speedup vs baseline: 2.2868x; 1.6587x over previous
//
#include <hip/hip_runtime.h>

typedef unsigned short u16;
typedef unsigned int   u32;

typedef __attribute__((ext_vector_type(8))) __bf16 bf16x8;
typedef __attribute__((ext_vector_type(4))) float  f32x4;

__device__ __forceinline__ u16 f2bf(float f) {
  union { float f; u32 u; } v; v.f = f;
  return (u16)((v.u + 0x7fffu + ((v.u >> 16) & 1u)) >> 16);
}

__device__ __forceinline__ void gl2lds16(const void* g, void* l) {
  __builtin_amdgcn_global_load_lds(
      (const __attribute__((address_space(1))) u32*)g,
      (__attribute__((address_space(3))) u32*)l, 16, 0, 0);
}

// ---------- W1 [K=1024][N=1024] f32 -> W1s pre-swizzled bf16 ----------
// W1s[kt][n][kk ^ ((n>>1)&3)<<3], kt = k>>5, kk = k&31. A linear 32KB-chunk
// copy of tile kt into LDS then gives the swizzled [n][kk] layout directly.
__global__ __launch_bounds__(256) void transpose_w1_kernel(
    const float* __restrict__ W1, u16* __restrict__ W1s) {
  __shared__ float tile[64][65];
  const int k0 = blockIdx.x * 64, n0 = blockIdx.y * 64;
  const int tx = threadIdx.x & 63, ty = threadIdx.x >> 6;
#pragma unroll
  for (int i = 0; i < 16; ++i) {
    int r = ty + i * 4;
    tile[r][tx] = W1[(k0 + r) * 1024 + n0 + tx];
  }
  __syncthreads();
#pragma unroll
  for (int i = 0; i < 16; ++i) {
    int r = ty * 16 + i;
    int n = n0 + r;
    int k = k0 + tx;
    int kt = k >> 5, kk = k & 31;
    W1s[kt * 32768 + n * 32 + (kk ^ (((n >> 1) & 3) << 3))] = f2bf(tile[tx][r]);
  }
}

// ---------- pd[b][d] = dec[b]·W2[:,d] + W2_b[d] + W1_b[d] ----------
__global__ __launch_bounds__(256) void proj_dec_kernel(
    const float* __restrict__ dec, const float* __restrict__ W2,
    const float* __restrict__ W2b, const float* __restrict__ W1b,
    float* __restrict__ pd) {
  __shared__ float sdec[64 * 256];
  const int dl = threadIdx.x & 63;
  const int bg = threadIdx.x >> 6;
  const int d  = blockIdx.x * 64 + dl;
  float acc[16];
#pragma unroll
  for (int i = 0; i < 16; ++i) acc[i] = 0.f;
  for (int et = 0; et < 4; ++et) {
    __syncthreads();
#pragma unroll
    for (int i = 0; i < 64; ++i) {
      int flat = threadIdx.x + i * 256;
      sdec[flat] = dec[(flat >> 8) * 1024 + et * 256 + (flat & 255)];
    }
    __syncthreads();
    for (int e = 0; e < 256; ++e) {
      float w2 = W2[(et * 256 + e) * 1024 + d];
#pragma unroll
      for (int bb = 0; bb < 16; ++bb)
        acc[bb] += sdec[(bg * 16 + bb) * 256 + e] * w2;
    }
  }
  float bias = W2b[d] + W1b[d];
#pragma unroll
  for (int bb = 0; bb < 16; ++bb)
    pd[(bg * 16 + bb) * 1024 + d] = acc[bb] + bias;
}

// ---------- fused GEMM + tanh + V-dot -> scores ----------
// BM=64, BN=1024 (full N), BK=32, double-buffered 2-phase K-loop.
// 512 thr = 8 waves, wave w owns cols [w*128, w*128+128), all 64 rows.
// B: global_load_lds from pre-swizzled W1s (linear 64KB tile copy).
// A: reg-staged f32->bf16, swizzled ds_write. 12 ds_read : 32 MFMA /wave/tile.
__global__ __launch_bounds__(512, 2) void score_kernel(
    const float* __restrict__ enc, const u16* __restrict__ W1s,
    const float* __restrict__ pd, const float* __restrict__ Vw,
    float* __restrict__ scores) {
  __shared__ __align__(16) u16 Bs[2][1024 * 32];  // 2 x 64 KB
  __shared__ __align__(16) u16 As[2][64 * 32];    // 2 x 4 KB
  __shared__ float sc2[8][64];

  const int  tid  = threadIdx.x;
  const int  lane = tid & 63;
  const int  wn   = tid >> 6;          // wave id = n-group 0..7
  const int  l15  = lane & 15, l4 = lane >> 4;
  const long row0 = (long)blockIdx.x * 64;
  const int  b    = blockIdx.x >> 5;   // 32 blocks per batch

  // A staging: thread t loads float4 at (row am, k akq..akq+3) of the tile
  const int am   = tid >> 3;
  const int akq  = (tid & 7) * 4;
  const int aidx = am * 32 + (akq ^ (((am >> 1) & 3) << 3));
  const float* aptr = enc + (size_t)(row0 + am) * 1024 + akq;

  f32x4 acc[4][8];
#pragma unroll
  for (int mf = 0; mf < 4; ++mf)
#pragma unroll
    for (int nf = 0; nf < 8; ++nf) acc[mf][nf] = (f32x4){0, 0, 0, 0};

  // fragment k-offset (swizzle depends only on l15 since rows step by 16)
  const int kA = (l4 * 8) ^ (((l15 >> 1) & 3) << 3);

  // prologue: stage tile 0
  {
    float4 av = *reinterpret_cast<const float4*>(aptr);
#pragma unroll
    for (int j = 0; j < 8; ++j)
      gl2lds16(W1s + j * 4096 + tid * 8, &Bs[0][j * 4096 + tid * 8]);
    u32 p0 = (u32)f2bf(av.x) | ((u32)f2bf(av.y) << 16);
    u32 p1 = (u32)f2bf(av.z) | ((u32)f2bf(av.w) << 16);
    uint2 pk; pk.x = p0; pk.y = p1;
    *reinterpret_cast<uint2*>(&As[0][aidx]) = pk;
  }
  __syncthreads();

  for (int kt = 0; kt < 32; ++kt) {
    const int cur = kt & 1, nxt = cur ^ 1;
    float4 av;
    if (kt < 31) {  // issue next tile's loads before compute
      av = *reinterpret_cast<const float4*>(aptr + (kt + 1) * 32);
      const u16* bsrc = W1s + (kt + 1) * 32768;
#pragma unroll
      for (int j = 0; j < 8; ++j)
        gl2lds16(bsrc + j * 4096 + tid * 8, &Bs[nxt][j * 4096 + tid * 8]);
    }
    // compute current tile
    bf16x8 af[4];
#pragma unroll
    for (int mf = 0; mf < 4; ++mf)
      af[mf] = *reinterpret_cast<const bf16x8*>(&As[cur][(mf * 16 + l15) * 32 + kA]);
#pragma unroll
    for (int nf = 0; nf < 8; ++nf) {
      bf16x8 bfr = *reinterpret_cast<const bf16x8*>(
          &Bs[cur][(wn * 128 + nf * 16 + l15) * 32 + kA]);
#pragma unroll
      for (int mf = 0; mf < 4; ++mf)
        acc[mf][nf] = __builtin_amdgcn_mfma_f32_16x16x32_bf16(af[mf], bfr, acc[mf][nf], 0, 0, 0);
    }
    if (kt < 31) {  // finish A staging (load has had the MFMA block to land)
      u32 p0 = (u32)f2bf(av.x) | ((u32)f2bf(av.y) << 16);
      u32 p1 = (u32)f2bf(av.z) | ((u32)f2bf(av.w) << 16);
      uint2 pk; pk.x = p0; pk.y = p1;
      *reinterpret_cast<uint2*>(&As[nxt][aidx]) = pk;
    }
    __syncthreads();
  }

  // epilogue: v = acc + pd; part += tanh(v) * Vw; reduce over 16 col-lanes
  float pd8[8], vw8[8];
#pragma unroll
  for (int nf = 0; nf < 8; ++nf) {
    int c = wn * 128 + nf * 16 + l15;
    pd8[nf] = pd[b * 1024 + c];
    vw8[nf] = Vw[c];
  }
#pragma unroll
  for (int mf = 0; mf < 4; ++mf)
#pragma unroll
    for (int r = 0; r < 4; ++r) {
      float s = 0.f;
#pragma unroll
      for (int nf = 0; nf < 8; ++nf) {
        float v = acc[mf][nf][r] + pd8[nf];
        float e = __expf(2.f * v);
        s += (1.f - 2.f * __builtin_amdgcn_rcpf(e + 1.f)) * vw8[nf];
      }
      s += __shfl_xor(s, 1);
      s += __shfl_xor(s, 2);
      s += __shfl_xor(s, 4);
      s += __shfl_xor(s, 8);
      if (l15 == 0) sc2[wn][mf * 16 + l4 * 4 + r] = s;
    }
  __syncthreads();
  if (tid < 64) {
    float s = 0.f;
#pragma unroll
    for (int w = 0; w < 8; ++w) s += sc2[w][tid];
    scores[row0 + tid] = s;  // V_b omitted: uniform shift cancels in softmax
  }
}

// ---------- softmax over S=2048 per batch ----------
__global__ __launch_bounds__(512) void softmax_kernel(
    const float* __restrict__ scores, float* __restrict__ wout) {
  __shared__ float redm[8], reds[8];
  const int b = blockIdx.x, tid = threadIdx.x;
  float4 v = *reinterpret_cast<const float4*>(scores + b * 2048 + tid * 4);
  float m = fmaxf(fmaxf(v.x, v.y), fmaxf(v.z, v.w));
  for (int off = 32; off; off >>= 1) m = fmaxf(m, __shfl_xor(m, off));
  if ((tid & 63) == 0) redm[tid >> 6] = m;
  __syncthreads();
  m = fmaxf(fmaxf(fmaxf(redm[0], redm[1]), fmaxf(redm[2], redm[3])),
            fmaxf(fmaxf(redm[4], redm[5]), fmaxf(redm[6], redm[7])));
  float e0 = __expf(v.x - m), e1 = __expf(v.y - m);
  float e2 = __expf(v.z - m), e3 = __expf(v.w - m);
  float s = e0 + e1 + e2 + e3;
  for (int off = 32; off; off >>= 1) s += __shfl_xor(s, off);
  if ((tid & 63) == 0) reds[tid >> 6] = s;
  __syncthreads();
  s = reds[0] + reds[1] + reds[2] + reds[3] + reds[4] + reds[5] + reds[6] + reds[7];
  float inv = 1.0f / s;
  float4 o; o.x = e0 * inv; o.y = e1 * inv; o.z = e2 * inv; o.w = e3 * inv;
  *reinterpret_cast<float4*>(wout + b * 2048 + tid * 4) = o;
}

// ---------- context partials ----------
__global__ __launch_bounds__(256) void context_partial_kernel(
    const float* __restrict__ w, const float* __restrict__ enc,
    float* __restrict__ cpart) {
  const int b  = blockIdx.x;   // 64
  const int es = blockIdx.y;   // 4
  const int ss = blockIdx.z;   // 8
  const int e  = es * 256 + threadIdx.x;
  const float* ep = enc + ((size_t)b * 2048 + (size_t)ss * 256) * 1024 + e;
  const float* wp = w + b * 2048 + ss * 256;
  float acc = 0.f;
#pragma unroll 8
  for (int s = 0; s < 256; ++s)
    acc += wp[s] * ep[(size_t)s * 1024];
  cpart[((size_t)(b * 8 + ss)) * 1024 + e] = acc;
}

__global__ __launch_bounds__(256) void context_reduce_kernel(
    const float* __restrict__ cpart, float* __restrict__ ctx) {
  const int i = blockIdx.x * 256 + threadIdx.x;
  const int b = i >> 10, e = i & 1023;
  float s = 0.f;
#pragma unroll
  for (int j = 0; j < 8; ++j) s += cpart[(size_t)(b * 8 + j) * 1024 + e];
  ctx[i] = s;
}

extern "C" void kernel_launch(void* const* d_in, const int* in_sizes, int n_in,
                              void* d_out, int out_size, void* d_ws, size_t ws_size,
                              hipStream_t stream) {
  const float* enc = (const float*)d_in[0];
  const float* dec = (const float*)d_in[1];
  const float* W1w = (const float*)d_in[2];
  const float* W1b = (const float*)d_in[3];
  const float* W2w = (const float*)d_in[4];
  const float* W2b = (const float*)d_in[5];
  const float* Vw  = (const float*)d_in[6];
  // d_in[7] = V_b: uniform shift, cancels in softmax.

  char* ws = (char*)d_ws;
  u16*   W1s    = (u16*)ws;                                  // 2 MB
  float* cpart  = (float*)ws;                                // reuses W1s after scores
  float* pd     = (float*)(ws + (2u << 20));                 // 256 KB
  float* scores = (float*)(ws + (2u << 20) + (256u << 10));  // 512 KB
  float* wout = (float*)d_out;
  float* ctx  = (float*)d_out + 64 * 2048;

  transpose_w1_kernel<<<dim3(16, 16), 256, 0, stream>>>(W1w, W1s);
  proj_dec_kernel<<<16, 256, 0, stream>>>(dec, W2w, W2b, W1b, pd);
  score_kernel<<<2048, 512, 0, stream>>>(enc, W1s, pd, Vw, scores);
  softmax_kernel<<<64, 512, 0, stream>>>(scores, wout);
  context_partial_kernel<<<dim3(64, 4, 8), 256, 0, stream>>>(wout, enc, cpart);
  context_reduce_kernel<<<256, 256, 0, stream>>>(cpart, ctx);
}